// Round 4
// baseline (3581.730 us; speedup 1.0000x reference)
//
#include <hip/hip_runtime.h>
#include <math.h>

#define TB1 4
#define TB2 16

typedef __attribute__((ext_vector_type(8))) short s8v;
typedef __attribute__((ext_vector_type(4))) short s4v;
typedef __attribute__((ext_vector_type(4))) float f4v;

__device__ __forceinline__ float4 ldg4(const float* p) { return *(const float4*)p; }

// fp32 -> bf16 round-to-nearest-even
__device__ __forceinline__ short f2b(float f) {
    union { float f; unsigned u; } v; v.f = f;
    unsigned r = v.u + 0x7fffu + ((v.u >> 16) & 1u);
    return (short)(r >> 16);
}
__device__ __forceinline__ s8v pack8(float4 a, float4 b) {
    s8v r;
    r[0] = f2b(a.x); r[1] = f2b(a.y); r[2] = f2b(a.z); r[3] = f2b(a.w);
    r[4] = f2b(b.x); r[5] = f2b(b.y); r[6] = f2b(b.z); r[7] = f2b(b.w);
    return r;
}

// ---------------------------------------------------------------------------
// Kernel 1: up router (verbatim, bitwise) + per-wave fp32 experts + gelu.
// Expert phase: lane o owns output row o. t1[o][*] = sum_i A[o][i] x[i][*]
// (A per-lane from L2, x broadcast from LDS) stays in registers; then
// Y[o][p] = pw * sum_j t1[o][j] B[p][j]. Zero barriers, zero LDS scratch,
// zero cross-lane traffic. Per-(o,j)/(o,p) accumulation chains match the
// previous verified code's serial order (h stays fp32-class; only reorder-
// level ulp drift, which the down router tolerates).
// ---------------------------------------------------------------------------
__global__ __launch_bounds__(256, 3) void up_kernel(
    const float* __restrict__ x, const float* __restrict__ Wup,
    const float* __restrict__ Aup, const float* __restrict__ Bup,
    const float* __restrict__ scale_up, const float* __restrict__ bias_up,
    float* __restrict__ h)
{
    __shared__ __align__(16) float xs[TB1 * 1024];
    __shared__ __align__(16) float wcs[64 * 68];
    __shared__ __align__(16) float lp[4 * TB1 * 64];
    __shared__ __align__(16) float logits[TB1 * 64];
    __shared__ int   seli[TB1 * 2];
    __shared__ float selp[TB1 * 2];

    const int tid = threadIdx.x;
    const long long blockTok = (long long)blockIdx.x * TB1;

    // ---- stage x rows (verbatim) ----
    {
        const float* src = x + blockTok * 1024;
#pragma unroll
        for (int q = 0; q < TB1; ++q) {
            int flat = tid * 4 + q * 1024;
            *(float4*)&xs[flat] = ldg4(src + flat);
        }
    }

    // ---- router: logits = x . Wup^T (verbatim, bitwise) ----
    float racc0[TB1] = {0.f, 0.f, 0.f, 0.f};
    float racc1[TB1] = {0.f, 0.f, 0.f, 0.f};
    const int e2 = tid & 31, jsl = tid >> 5;
    for (int kc = 0; kc < 1024; kc += 64) {
        __syncthreads();
#pragma unroll
        for (int r = 0; r < 4; ++r) {
            int row = (tid >> 4) + r * 16;
            int col = (tid & 15) * 4;
            *(float4*)&wcs[row * 68 + col] = ldg4(&Wup[row * 1024 + kc + col]);
        }
        __syncthreads();
#pragma unroll
        for (int ks = 0; ks < 2; ++ks) {
            int kk = jsl * 8 + ks * 4;
            float4 w0 = *(float4*)&wcs[e2 * 68 + kk];
            float4 w1 = *(float4*)&wcs[(e2 + 32) * 68 + kk];
#pragma unroll
            for (int t = 0; t < TB1; ++t) {
                float4 xv = *(float4*)&xs[t * 1024 + kc + kk];
                racc0[t] += w0.x * xv.x + w0.y * xv.y + w0.z * xv.z + w0.w * xv.w;
                racc1[t] += w1.x * xv.x + w1.y * xv.y + w1.z * xv.z + w1.w * xv.w;
            }
        }
    }
#pragma unroll
    for (int t = 0; t < TB1; ++t) {
        racc0[t] += __shfl_xor(racc0[t], 32);
        racc1[t] += __shfl_xor(racc1[t], 32);
    }
    {
        const int wv = tid >> 6;
        if ((tid & 32) == 0) {
#pragma unroll
            for (int t = 0; t < TB1; ++t) {
                lp[(wv * TB1 + t) * 64 + e2]      = racc0[t];
                lp[(wv * TB1 + t) * 64 + e2 + 32] = racc1[t];
            }
        }
    }
    __syncthreads();
    logits[tid] = lp[0 * 256 + tid] + lp[1 * 256 + tid] + lp[2 * 256 + tid] + lp[3 * 256 + tid];
    __syncthreads();
    if (tid < TB1) {
        const float* lg = &logits[tid * 64];
        float v0 = -1e30f; int i0 = 0;
        for (int q = 0; q < 64; ++q) { float v = lg[q]; if (v > v0) { v0 = v; i0 = q; } }
        float v1 = -1e30f; int i1 = 0;
        for (int q = 0; q < 64; ++q) { if (q == i0) continue; float v = lg[q]; if (v > v1) { v1 = v; i1 = q; } }
        float r = expf(v1 - v0);
        float inv = 1.f / (1.f + r);
        seli[tid * 2] = i0; seli[tid * 2 + 1] = i1;
        selp[tid * 2] = inv; selp[tid * 2 + 1] = r * inv;
    }
    __syncthreads();

    // ---- experts: per-wave fp32, one token per wave, barrier-free ----
    const float sc_up = scale_up[0];
    const int wv = tid >> 6, lane = tid & 63;
    const int t = wv;
    const long long tok = blockTok + t;
    const float* xrow = &xs[t * 1024];   // x [32 i][32 j] in LDS (broadcast reads)

    const int   ex0 = seli[t * 2 + 0], ex1 = seli[t * 2 + 1];
    const float pw0 = selp[t * 2 + 0], pw1 = selp[t * 2 + 1];
    const float* A0 = Aup + (long long)ex0 * 2048 + lane * 32;  // A row 'lane'
    const float* A1 = Aup + (long long)ex1 * 2048 + lane * 32;
    const float* B0 = Bup + (long long)ex0 * 2048;              // [64 p][32 j]
    const float* B1 = Bup + (long long)ex1 * 2048;

    // stage 1 (both experts share the x reads): t1e[o=lane][j], j in 8 float4s
    float4 t10[8], t11[8];
#pragma unroll
    for (int q = 0; q < 8; ++q) {
        t10[q] = make_float4(0.f, 0.f, 0.f, 0.f);
        t11[q] = make_float4(0.f, 0.f, 0.f, 0.f);
    }
#pragma unroll 4
    for (int i = 0; i < 32; ++i) {
        float a0 = A0[i];
        float a1 = A1[i];
#pragma unroll
        for (int q = 0; q < 8; ++q) {
            float4 xv = *(const float4*)&xrow[i * 32 + q * 4];
            t10[q].x += a0 * xv.x; t10[q].y += a0 * xv.y;
            t10[q].z += a0 * xv.z; t10[q].w += a0 * xv.w;
            t11[q].x += a1 * xv.x; t11[q].y += a1 * xv.y;
            t11[q].z += a1 * xv.z; t11[q].w += a1 * xv.w;
        }
    }

    // stage 2 + gelu epilogue, p-blocks of 8 (all register-static indexing)
    float* hrow = h + tok * 4096 + lane * 64;
    const float* brow = bias_up + lane * 64;
#pragma unroll 1
    for (int pb = 0; pb < 8; ++pb) {
        float yb[8];
#pragma unroll
        for (int u = 0; u < 8; ++u) yb[u] = 0.f;
#pragma unroll
        for (int u = 0; u < 8; ++u) {
            const float* Bp = B0 + (pb * 8 + u) * 32;
            float s = 0.f;
#pragma unroll
            for (int q = 0; q < 8; ++q) {
                float4 bv = ldg4(Bp + q * 4);
                s += t10[q].x * bv.x + t10[q].y * bv.y + t10[q].z * bv.z + t10[q].w * bv.w;
            }
            yb[u] += pw0 * s;
        }
#pragma unroll
        for (int u = 0; u < 8; ++u) {
            const float* Bp = B1 + (pb * 8 + u) * 32;
            float s = 0.f;
#pragma unroll
            for (int q = 0; q < 8; ++q) {
                float4 bv = ldg4(Bp + q * 4);
                s += t11[q].x * bv.x + t11[q].y * bv.y + t11[q].z * bv.z + t11[q].w * bv.w;
            }
            yb[u] += pw1 * s;
        }
#pragma unroll
        for (int u = 0; u < 8; ++u) {
            float v = yb[u] * sc_up;
            float z = v + brow[pb * 8 + u];
            yb[u] = 0.5f * z * (1.0f + erff(z * 0.70710678118654752f));
        }
        float4 s0 = make_float4(yb[0], yb[1], yb[2], yb[3]);
        float4 s1 = make_float4(yb[4], yb[5], yb[6], yb[7]);
        *(float4*)(hrow + pb * 8)     = s0;
        *(float4*)(hrow + pb * 8 + 4) = s1;
    }
}

// ---------------------------------------------------------------------------
// Kernel 2: down router + down experts (bf16 MFMA, per-wave)
// [VERBATIM R0 baseline version, TB2=16 — measured ~187.5 us]
// ---------------------------------------------------------------------------
__global__ __launch_bounds__(256, 2) void down_kernel(
    const float* __restrict__ h,        // [N][4096]
    const float* __restrict__ Wdn,      // [64][4096]
    const float* __restrict__ Adn,      // [64][32][64]
    const float* __restrict__ Bdn,      // [64][32][64]
    const float* __restrict__ scale_dn, // [1]
    const float* __restrict__ bias_dn,  // [1024]
    float* __restrict__ out)            // [N][1024]
{
    __shared__ __align__(16) float wcs[64 * 68];    // 17.4 KB
    __shared__ __align__(16) float hcs[16 * 68];    // 4.3 KB
    __shared__ __align__(16) float lp[4 * 16 * 64]; // 16.4 KB
    __shared__ __align__(16) float logits[TB2 * 64];
    __shared__ __align__(16) short wt[4][32 * 72];  // per-wave W^T bf16 [p][i]
    __shared__ int   seli[TB2 * 2];
    __shared__ float selp[TB2 * 2];

    const int tid = threadIdx.x;
    const long long tokbase = (long long)blockIdx.x * TB2;

    // ---- down router: 4 experts per thread, k-slice = one float4 ----
    const int e4 = tid & 15, jsl = tid >> 4; // jsl 0..15
    float r0[16], r1[16], r2[16], r3[16];
#pragma unroll
    for (int t = 0; t < 16; ++t) { r0[t] = 0.f; r1[t] = 0.f; r2[t] = 0.f; r3[t] = 0.f; }

    for (int kc = 0; kc < 4096; kc += 64) {
        __syncthreads();
#pragma unroll
        for (int r = 0; r < 4; ++r) {
            int row = (tid >> 4) + r * 16;
            int col = (tid & 15) * 4;
            *(float4*)&wcs[row * 68 + col] = ldg4(&Wdn[row * 4096 + kc + col]);
        }
        {
            int t = tid >> 4, c = (tid & 15) * 4;
            *(float4*)&hcs[t * 68 + c] = ldg4(&h[(tokbase + t) * 4096 + kc + c]);
        }
        __syncthreads();
        const int kk = jsl * 4;
        float4 w0 = *(float4*)&wcs[(e4)      * 68 + kk];
        float4 w1 = *(float4*)&wcs[(e4 + 16) * 68 + kk];
        float4 w2 = *(float4*)&wcs[(e4 + 32) * 68 + kk];
        float4 w3 = *(float4*)&wcs[(e4 + 48) * 68 + kk];
#pragma unroll
        for (int t = 0; t < 16; ++t) {
            float4 hv = *(float4*)&hcs[t * 68 + kk];
            r0[t] += w0.x * hv.x + w0.y * hv.y + w0.z * hv.z + w0.w * hv.w;
            r1[t] += w1.x * hv.x + w1.y * hv.y + w1.z * hv.z + w1.w * hv.w;
            r2[t] += w2.x * hv.x + w2.y * hv.y + w2.z * hv.z + w2.w * hv.w;
            r3[t] += w3.x * hv.x + w3.y * hv.y + w3.z * hv.z + w3.w * hv.w;
        }
    }
    // reduce over the wave's 4 k-slices (lanes xor 16, 32)
#pragma unroll
    for (int t = 0; t < 16; ++t) {
        r0[t] += __shfl_xor(r0[t], 16); r0[t] += __shfl_xor(r0[t], 32);
        r1[t] += __shfl_xor(r1[t], 16); r1[t] += __shfl_xor(r1[t], 32);
        r2[t] += __shfl_xor(r2[t], 16); r2[t] += __shfl_xor(r2[t], 32);
        r3[t] += __shfl_xor(r3[t], 16); r3[t] += __shfl_xor(r3[t], 32);
    }
    {
        const int wv = tid >> 6, g = (tid >> 4) & 3;
        float* dst = &lp[wv * 1024];
        if (g == 0) {
#pragma unroll
            for (int t = 0; t < 16; ++t) dst[t * 64 + e4] = r0[t];
        } else if (g == 1) {
#pragma unroll
            for (int t = 0; t < 16; ++t) dst[t * 64 + 16 + e4] = r1[t];
        } else if (g == 2) {
#pragma unroll
            for (int t = 0; t < 16; ++t) dst[t * 64 + 32 + e4] = r2[t];
        } else {
#pragma unroll
            for (int t = 0; t < 16; ++t) dst[t * 64 + 48 + e4] = r3[t];
        }
    }
    __syncthreads();
#pragma unroll
    for (int q = 0; q < 4; ++q) {
        int pair = tid + q * 256;
        logits[pair] = lp[0 * 1024 + pair] + lp[1 * 1024 + pair] +
                       lp[2 * 1024 + pair] + lp[3 * 1024 + pair];
    }
    __syncthreads();
    if (tid < TB2) {
        const float* lg = &logits[tid * 64];
        float v0 = -1e30f; int i0 = 0;
        for (int q = 0; q < 64; ++q) { float v = lg[q]; if (v > v0) { v0 = v; i0 = q; } }
        float v1 = -1e30f; int i1 = 0;
        for (int q = 0; q < 64; ++q) { if (q == i0) continue; float v = lg[q]; if (v > v1) { v1 = v; i1 = q; } }
        float r = expf(v1 - v0);
        float inv = 1.f / (1.f + r);
        seli[tid * 2] = i0; seli[tid * 2 + 1] = i1;
        selp[tid * 2] = inv; selp[tid * 2 + 1] = r * inv;
    }
    __syncthreads();

    // ---- down experts: per-wave MFMA, no barriers ----
    const float sc_dn = scale_dn[0];
    const int wv = tid >> 6;
    const int lane = tid & 63;
    const int m = lane & 15, quad = lane >> 4;
    short* wtw = &wt[wv][0]; // [32 p][72 i] bf16

    const f4v zf = {0.f, 0.f, 0.f, 0.f};

#pragma unroll 1
    for (int tt = 0; tt < 4; ++tt) {
        const int t = wv * 4 + tt;
        const long long tok = tokbase + t;
        const float* xrow = h + tok * 4096; // X[64 i][64 j], j contiguous

        s8v xf[8];
#pragma unroll
        for (int mt = 0; mt < 4; ++mt)
#pragma unroll
            for (int ks = 0; ks < 2; ++ks) {
                int base = (mt * 16 + m) * 64 + ks * 32 + quad * 8;
                xf[mt * 2 + ks] = pack8(ldg4(xrow + base), ldg4(xrow + base + 4));
            }

        f4v y00 = zf, y01 = zf, y10 = zf, y11 = zf;

        for (int ke = 0; ke < 2; ++ke) {
            const int ex = seli[t * 2 + ke];
            const float pw = selp[t * 2 + ke];
            const float* A = Adn + ex * 2048; // [32 o][64 i]
            const float* B = Bdn + ex * 2048; // [32 p][64 j]

            // ---- stage 1: W[i][p] = sum_j X[i][j] * B[p][j] ----
            f4v wd[8];
#pragma unroll
            for (int ks = 0; ks < 2; ++ks) {
                s8v bf0, bf1;
                {
                    int base = (0 * 16 + m) * 64 + ks * 32 + quad * 8;
                    bf0 = pack8(ldg4(B + base), ldg4(B + base + 4));
                    base = (1 * 16 + m) * 64 + ks * 32 + quad * 8;
                    bf1 = pack8(ldg4(B + base), ldg4(B + base + 4));
                }
#pragma unroll
                for (int mt = 0; mt < 4; ++mt) {
                    wd[mt * 2 + 0] = __builtin_amdgcn_mfma_f32_16x16x32_bf16(
                        xf[mt * 2 + ks], bf0, ks == 0 ? zf : wd[mt * 2 + 0], 0, 0, 0);
                    wd[mt * 2 + 1] = __builtin_amdgcn_mfma_f32_16x16x32_bf16(
                        xf[mt * 2 + ks], bf1, ks == 0 ? zf : wd[mt * 2 + 1], 0, 0, 0);
                }
            }
#pragma unroll
            for (int mt = 0; mt < 4; ++mt)
#pragma unroll
                for (int pt = 0; pt < 2; ++pt) {
                    f4v w = wd[mt * 2 + pt];
                    s4v s;
                    s[0] = f2b(w[0] * pw); s[1] = f2b(w[1] * pw);
                    s[2] = f2b(w[2] * pw); s[3] = f2b(w[3] * pw);
                    *(s4v*)&wtw[(pt * 16 + m) * 72 + mt * 16 + quad * 4] = s;
                }

            // ---- stage 2: Y[o][p] += sum_i A[o][i] * (pw*W)[i][p] ----
#pragma unroll
            for (int ks = 0; ks < 2; ++ks) {
                s8v wb0 = *(s8v*)&wtw[(0 * 16 + m) * 72 + ks * 32 + quad * 8];
                s8v wb1 = *(s8v*)&wtw[(1 * 16 + m) * 72 + ks * 32 + quad * 8];
                s8v af0, af1;
                {
                    int base = (0 * 16 + m) * 64 + ks * 32 + quad * 8;
                    af0 = pack8(ldg4(A + base), ldg4(A + base + 4));
                    base = (1 * 16 + m) * 64 + ks * 32 + quad * 8;
                    af1 = pack8(ldg4(A + base), ldg4(A + base + 4));
                }
                y00 = __builtin_amdgcn_mfma_f32_16x16x32_bf16(af0, wb0, y00, 0, 0, 0);
                y01 = __builtin_amdgcn_mfma_f32_16x16x32_bf16(af0, wb1, y01, 0, 0, 0);
                y10 = __builtin_amdgcn_mfma_f32_16x16x32_bf16(af1, wb0, y10, 0, 0, 0);
                y11 = __builtin_amdgcn_mfma_f32_16x16x32_bf16(af1, wb1, y11, 0, 0, 0);
            }
        }

        float* orow = out + tok * 1024;
#pragma unroll
        for (int r = 0; r < 4; ++r) {
            int o0 = quad * 4 + r;
            int f00 = o0 * 32 + m;
            orow[f00]            = y00[r] * sc_dn + bias_dn[f00];
            orow[f00 + 16]       = y01[r] * sc_dn + bias_dn[f00 + 16];
            int f10 = (o0 + 16) * 32 + m;
            orow[f10]            = y10[r] * sc_dn + bias_dn[f10];
            orow[f10 + 16]       = y11[r] * sc_dn + bias_dn[f10 + 16];
        }
    }
}

extern "C" void kernel_launch(void* const* d_in, const int* in_sizes, int n_in,
                              void* d_out, int out_size, void* d_ws, size_t ws_size,
                              hipStream_t stream) {
    const float* x   = (const float*)d_in[0];
    const float* Wup = (const float*)d_in[1];
    const float* Aup = (const float*)d_in[2];
    const float* Bup = (const float*)d_in[3];
    const float* scu = (const float*)d_in[4];
    const float* biu = (const float*)d_in[5];
    const float* Wdn = (const float*)d_in[6];
    const float* Adn = (const float*)d_in[7];
    const float* Bdn = (const float*)d_in[8];
    const float* scd = (const float*)d_in[9];
    const float* bid = (const float*)d_in[10];
    float* out = (float*)d_out;
    float* h   = (float*)d_ws;   // [N][4096] fp32 = 128 MB for N=8192

    const int N = in_sizes[0] / 1024;

    hipLaunchKernelGGL(up_kernel, dim3(N / TB1), dim3(256), 0, stream,
                       x, Wup, Aup, Bup, scu, biu, h);
    hipLaunchKernelGGL(down_kernel, dim3(N / TB2), dim3(256), 0, stream,
                       h, Wdn, Adn, Bdn, scd, bid, out);
}

// Round 5
// 509.793 us; speedup vs baseline: 7.0259x; 7.0259x over previous
//
#include <hip/hip_runtime.h>
#include <math.h>

#define TB1 4
#define TB2 16

typedef __attribute__((ext_vector_type(8))) short s8v;
typedef __attribute__((ext_vector_type(4))) short s4v;
typedef __attribute__((ext_vector_type(4))) float f4v;

__device__ __forceinline__ float4 ldg4(const float* p) { return *(const float4*)p; }

__device__ __forceinline__ f4v splat4(float s) { f4v v = {s, s, s, s}; return v; }

// fp32 -> bf16 round-to-nearest-even
__device__ __forceinline__ short f2b(float f) {
    union { float f; unsigned u; } v; v.f = f;
    unsigned r = v.u + 0x7fffu + ((v.u >> 16) & 1u);
    return (short)(r >> 16);
}
__device__ __forceinline__ s8v pack8(float4 a, float4 b) {
    s8v r;
    r[0] = f2b(a.x); r[1] = f2b(a.y); r[2] = f2b(a.z); r[3] = f2b(a.w);
    r[4] = f2b(b.x); r[5] = f2b(b.y); r[6] = f2b(b.z); r[7] = f2b(b.w);
    return r;
}

// dot of 32 floats held as 8 named f4v against a 32-float row (uniform addr)
__device__ __forceinline__ float dot32(const float* Bp,
    f4v t0, f4v t1, f4v t2, f4v t3, f4v t4, f4v t5, f4v t6, f4v t7)
{
    f4v s;
    s  = t0 * *(const f4v*)(Bp + 0);
    s += t1 * *(const f4v*)(Bp + 4);
    s += t2 * *(const f4v*)(Bp + 8);
    s += t3 * *(const f4v*)(Bp + 12);
    s += t4 * *(const f4v*)(Bp + 16);
    s += t5 * *(const f4v*)(Bp + 20);
    s += t6 * *(const f4v*)(Bp + 24);
    s += t7 * *(const f4v*)(Bp + 28);
    return (s[0] + s[1]) + (s[2] + s[3]);
}

// ---------------------------------------------------------------------------
// Kernel 1: up router (verbatim R0, bitwise) + per-wave fp32 experts + gelu.
// Expert phase: lane o owns output row o. t1[o][*] = sum_i A[o][i] x[i][*]
// in 16 NAMED f4v registers (R4 lesson: arrays of vectors -> scratch, 9GB
// HBM traffic). B-row reads made wave-uniform via readfirstlane(ex) so they
// go to the scalar pipe. Zero barriers, zero LDS scratch in expert phase.
// h is fp32 with reorder-level ulp drift only (R4 passed with identical
// absmax => down router tolerates this).
// ---------------------------------------------------------------------------
__global__ __launch_bounds__(256, 2) void up_kernel(
    const float* __restrict__ x, const float* __restrict__ Wup,
    const float* __restrict__ Aup, const float* __restrict__ Bup,
    const float* __restrict__ scale_up, const float* __restrict__ bias_up,
    float* __restrict__ h)
{
    __shared__ __align__(16) float xs[TB1 * 1024];
    __shared__ __align__(16) float wcs[64 * 68];
    __shared__ __align__(16) float lp[4 * TB1 * 64];
    __shared__ __align__(16) float logits[TB1 * 64];
    __shared__ int   seli[TB1 * 2];
    __shared__ float selp[TB1 * 2];

    const int tid = threadIdx.x;
    const long long blockTok = (long long)blockIdx.x * TB1;

    // ---- stage x rows (verbatim) ----
    {
        const float* src = x + blockTok * 1024;
#pragma unroll
        for (int q = 0; q < TB1; ++q) {
            int flat = tid * 4 + q * 1024;
            *(float4*)&xs[flat] = ldg4(src + flat);
        }
    }

    // ---- router: logits = x . Wup^T (verbatim, bitwise) ----
    float racc0[TB1] = {0.f, 0.f, 0.f, 0.f};
    float racc1[TB1] = {0.f, 0.f, 0.f, 0.f};
    const int e2 = tid & 31, jsl = tid >> 5;
    for (int kc = 0; kc < 1024; kc += 64) {
        __syncthreads();
#pragma unroll
        for (int r = 0; r < 4; ++r) {
            int row = (tid >> 4) + r * 16;
            int col = (tid & 15) * 4;
            *(float4*)&wcs[row * 68 + col] = ldg4(&Wup[row * 1024 + kc + col]);
        }
        __syncthreads();
#pragma unroll
        for (int ks = 0; ks < 2; ++ks) {
            int kk = jsl * 8 + ks * 4;
            float4 w0 = *(float4*)&wcs[e2 * 68 + kk];
            float4 w1 = *(float4*)&wcs[(e2 + 32) * 68 + kk];
#pragma unroll
            for (int t = 0; t < TB1; ++t) {
                float4 xv = *(float4*)&xs[t * 1024 + kc + kk];
                racc0[t] += w0.x * xv.x + w0.y * xv.y + w0.z * xv.z + w0.w * xv.w;
                racc1[t] += w1.x * xv.x + w1.y * xv.y + w1.z * xv.z + w1.w * xv.w;
            }
        }
    }
#pragma unroll
    for (int t = 0; t < TB1; ++t) {
        racc0[t] += __shfl_xor(racc0[t], 32);
        racc1[t] += __shfl_xor(racc1[t], 32);
    }
    {
        const int wv = tid >> 6;
        if ((tid & 32) == 0) {
#pragma unroll
            for (int t = 0; t < TB1; ++t) {
                lp[(wv * TB1 + t) * 64 + e2]      = racc0[t];
                lp[(wv * TB1 + t) * 64 + e2 + 32] = racc1[t];
            }
        }
    }
    __syncthreads();
    logits[tid] = lp[0 * 256 + tid] + lp[1 * 256 + tid] + lp[2 * 256 + tid] + lp[3 * 256 + tid];
    __syncthreads();
    if (tid < TB1) {
        const float* lg = &logits[tid * 64];
        float v0 = -1e30f; int i0 = 0;
        for (int q = 0; q < 64; ++q) { float v = lg[q]; if (v > v0) { v0 = v; i0 = q; } }
        float v1 = -1e30f; int i1 = 0;
        for (int q = 0; q < 64; ++q) { if (q == i0) continue; float v = lg[q]; if (v > v1) { v1 = v; i1 = q; } }
        float r = expf(v1 - v0);
        float inv = 1.f / (1.f + r);
        seli[tid * 2] = i0; seli[tid * 2 + 1] = i1;
        selp[tid * 2] = inv; selp[tid * 2 + 1] = r * inv;
    }
    __syncthreads();

    // ---- experts: per-wave fp32, one token per wave, barrier-free ----
    const float sc_up = scale_up[0];
    const int wv = tid >> 6, lane = tid & 63;
    const int t = wv;
    const long long tok = blockTok + t;
    const float* xrow = &xs[t * 1024];   // x [32 i][32 j] in LDS (broadcast reads)

    const int ex0 = __builtin_amdgcn_readfirstlane(seli[t * 2 + 0]);
    const int ex1 = __builtin_amdgcn_readfirstlane(seli[t * 2 + 1]);
    const float pw0 = selp[t * 2 + 0], pw1 = selp[t * 2 + 1];
    const float* Arow0 = Aup + (long long)ex0 * 2048 + lane * 32;  // A row 'lane'
    const float* Arow1 = Aup + (long long)ex1 * 2048 + lane * 32;
    const float* B0 = Bup + (long long)ex0 * 2048;                 // [64 p][32 j]
    const float* B1 = Bup + (long long)ex1 * 2048;

    // stage 1: t1[o=lane][j] in 16 NAMED f4v (no arrays -> no scratch)
    f4v ta0 = {0,0,0,0}, ta1 = {0,0,0,0}, ta2 = {0,0,0,0}, ta3 = {0,0,0,0};
    f4v ta4 = {0,0,0,0}, ta5 = {0,0,0,0}, ta6 = {0,0,0,0}, ta7 = {0,0,0,0};
    f4v tb0 = {0,0,0,0}, tb1 = {0,0,0,0}, tb2 = {0,0,0,0}, tb3 = {0,0,0,0};
    f4v tb4 = {0,0,0,0}, tb5 = {0,0,0,0}, tb6 = {0,0,0,0}, tb7 = {0,0,0,0};

#pragma unroll 1
    for (int g = 0; g < 8; ++g) {
        f4v a0 = *(const f4v*)(Arow0 + g * 4);
        f4v a1 = *(const f4v*)(Arow1 + g * 4);
#pragma unroll
        for (int u = 0; u < 4; ++u) {
            const float a0u = a0[u], a1u = a1[u];
            const float* xr = xrow + (g * 4 + u) * 32;
            f4v x0 = *(const f4v*)(xr + 0),  x1 = *(const f4v*)(xr + 4);
            f4v x2 = *(const f4v*)(xr + 8),  x3 = *(const f4v*)(xr + 12);
            f4v x4 = *(const f4v*)(xr + 16), x5 = *(const f4v*)(xr + 20);
            f4v x6 = *(const f4v*)(xr + 24), x7 = *(const f4v*)(xr + 28);
            f4v s0 = splat4(a0u), s1 = splat4(a1u);
            ta0 += s0 * x0; ta1 += s0 * x1; ta2 += s0 * x2; ta3 += s0 * x3;
            ta4 += s0 * x4; ta5 += s0 * x5; ta6 += s0 * x6; ta7 += s0 * x7;
            tb0 += s1 * x0; tb1 += s1 * x1; tb2 += s1 * x2; tb3 += s1 * x3;
            tb4 += s1 * x4; tb5 += s1 * x5; tb6 += s1 * x6; tb7 += s1 * x7;
        }
    }

    // stage 2 + gelu: p-blocks of 8, all named scalars
    float* hrow = h + tok * 4096 + lane * 64;
    const float* brow = bias_up + lane * 64;
#pragma unroll 1
    for (int pb = 0; pb < 8; ++pb) {
        const int p0 = pb * 8;
        float y0 = pw0 * dot32(B0 + (p0 + 0) * 32, ta0, ta1, ta2, ta3, ta4, ta5, ta6, ta7)
                 + pw1 * dot32(B1 + (p0 + 0) * 32, tb0, tb1, tb2, tb3, tb4, tb5, tb6, tb7);
        float y1 = pw0 * dot32(B0 + (p0 + 1) * 32, ta0, ta1, ta2, ta3, ta4, ta5, ta6, ta7)
                 + pw1 * dot32(B1 + (p0 + 1) * 32, tb0, tb1, tb2, tb3, tb4, tb5, tb6, tb7);
        float y2 = pw0 * dot32(B0 + (p0 + 2) * 32, ta0, ta1, ta2, ta3, ta4, ta5, ta6, ta7)
                 + pw1 * dot32(B1 + (p0 + 2) * 32, tb0, tb1, tb2, tb3, tb4, tb5, tb6, tb7);
        float y3 = pw0 * dot32(B0 + (p0 + 3) * 32, ta0, ta1, ta2, ta3, ta4, ta5, ta6, ta7)
                 + pw1 * dot32(B1 + (p0 + 3) * 32, tb0, tb1, tb2, tb3, tb4, tb5, tb6, tb7);
        float y4 = pw0 * dot32(B0 + (p0 + 4) * 32, ta0, ta1, ta2, ta3, ta4, ta5, ta6, ta7)
                 + pw1 * dot32(B1 + (p0 + 4) * 32, tb0, tb1, tb2, tb3, tb4, tb5, tb6, tb7);
        float y5 = pw0 * dot32(B0 + (p0 + 5) * 32, ta0, ta1, ta2, ta3, ta4, ta5, ta6, ta7)
                 + pw1 * dot32(B1 + (p0 + 5) * 32, tb0, tb1, tb2, tb3, tb4, tb5, tb6, tb7);
        float y6 = pw0 * dot32(B0 + (p0 + 6) * 32, ta0, ta1, ta2, ta3, ta4, ta5, ta6, ta7)
                 + pw1 * dot32(B1 + (p0 + 6) * 32, tb0, tb1, tb2, tb3, tb4, tb5, tb6, tb7);
        float y7 = pw0 * dot32(B0 + (p0 + 7) * 32, ta0, ta1, ta2, ta3, ta4, ta5, ta6, ta7)
                 + pw1 * dot32(B1 + (p0 + 7) * 32, tb0, tb1, tb2, tb3, tb4, tb5, tb6, tb7);

        f4v bb0 = *(const f4v*)(brow + p0);
        f4v bb1 = *(const f4v*)(brow + p0 + 4);
        float z;
        f4v o0, o1;
        z = y0 * sc_up + bb0[0]; o0[0] = 0.5f * z * (1.0f + erff(z * 0.70710678118654752f));
        z = y1 * sc_up + bb0[1]; o0[1] = 0.5f * z * (1.0f + erff(z * 0.70710678118654752f));
        z = y2 * sc_up + bb0[2]; o0[2] = 0.5f * z * (1.0f + erff(z * 0.70710678118654752f));
        z = y3 * sc_up + bb0[3]; o0[3] = 0.5f * z * (1.0f + erff(z * 0.70710678118654752f));
        z = y4 * sc_up + bb1[0]; o1[0] = 0.5f * z * (1.0f + erff(z * 0.70710678118654752f));
        z = y5 * sc_up + bb1[1]; o1[1] = 0.5f * z * (1.0f + erff(z * 0.70710678118654752f));
        z = y6 * sc_up + bb1[2]; o1[2] = 0.5f * z * (1.0f + erff(z * 0.70710678118654752f));
        z = y7 * sc_up + bb1[3]; o1[3] = 0.5f * z * (1.0f + erff(z * 0.70710678118654752f));
        *(f4v*)(hrow + p0)     = o0;
        *(f4v*)(hrow + p0 + 4) = o1;
    }
}

// ---------------------------------------------------------------------------
// Kernel 2: down router + down experts (bf16 MFMA, per-wave)
// [VERBATIM R0 baseline version, TB2=16 — measured ~187.5 us]
// ---------------------------------------------------------------------------
__global__ __launch_bounds__(256, 2) void down_kernel(
    const float* __restrict__ h,        // [N][4096]
    const float* __restrict__ Wdn,      // [64][4096]
    const float* __restrict__ Adn,      // [64][32][64]
    const float* __restrict__ Bdn,      // [64][32][64]
    const float* __restrict__ scale_dn, // [1]
    const float* __restrict__ bias_dn,  // [1024]
    float* __restrict__ out)            // [N][1024]
{
    __shared__ __align__(16) float wcs[64 * 68];    // 17.4 KB
    __shared__ __align__(16) float hcs[16 * 68];    // 4.3 KB
    __shared__ __align__(16) float lp[4 * 16 * 64]; // 16.4 KB
    __shared__ __align__(16) float logits[TB2 * 64];
    __shared__ __align__(16) short wt[4][32 * 72];  // per-wave W^T bf16 [p][i]
    __shared__ int   seli[TB2 * 2];
    __shared__ float selp[TB2 * 2];

    const int tid = threadIdx.x;
    const long long tokbase = (long long)blockIdx.x * TB2;

    // ---- down router: 4 experts per thread, k-slice = one float4 ----
    const int e4 = tid & 15, jsl = tid >> 4; // jsl 0..15
    float r0[16], r1[16], r2[16], r3[16];
#pragma unroll
    for (int t = 0; t < 16; ++t) { r0[t] = 0.f; r1[t] = 0.f; r2[t] = 0.f; r3[t] = 0.f; }

    for (int kc = 0; kc < 4096; kc += 64) {
        __syncthreads();
#pragma unroll
        for (int r = 0; r < 4; ++r) {
            int row = (tid >> 4) + r * 16;
            int col = (tid & 15) * 4;
            *(float4*)&wcs[row * 68 + col] = ldg4(&Wdn[row * 4096 + kc + col]);
        }
        {
            int t = tid >> 4, c = (tid & 15) * 4;
            *(float4*)&hcs[t * 68 + c] = ldg4(&h[(tokbase + t) * 4096 + kc + c]);
        }
        __syncthreads();
        const int kk = jsl * 4;
        float4 w0 = *(float4*)&wcs[(e4)      * 68 + kk];
        float4 w1 = *(float4*)&wcs[(e4 + 16) * 68 + kk];
        float4 w2 = *(float4*)&wcs[(e4 + 32) * 68 + kk];
        float4 w3 = *(float4*)&wcs[(e4 + 48) * 68 + kk];
#pragma unroll
        for (int t = 0; t < 16; ++t) {
            float4 hv = *(float4*)&hcs[t * 68 + kk];
            r0[t] += w0.x * hv.x + w0.y * hv.y + w0.z * hv.z + w0.w * hv.w;
            r1[t] += w1.x * hv.x + w1.y * hv.y + w1.z * hv.z + w1.w * hv.w;
            r2[t] += w2.x * hv.x + w2.y * hv.y + w2.z * hv.z + w2.w * hv.w;
            r3[t] += w3.x * hv.x + w3.y * hv.y + w3.z * hv.z + w3.w * hv.w;
        }
    }
    // reduce over the wave's 4 k-slices (lanes xor 16, 32)
#pragma unroll
    for (int t = 0; t < 16; ++t) {
        r0[t] += __shfl_xor(r0[t], 16); r0[t] += __shfl_xor(r0[t], 32);
        r1[t] += __shfl_xor(r1[t], 16); r1[t] += __shfl_xor(r1[t], 32);
        r2[t] += __shfl_xor(r2[t], 16); r2[t] += __shfl_xor(r2[t], 32);
        r3[t] += __shfl_xor(r3[t], 16); r3[t] += __shfl_xor(r3[t], 32);
    }
    {
        const int wv = tid >> 6, g = (tid >> 4) & 3;
        float* dst = &lp[wv * 1024];
        if (g == 0) {
#pragma unroll
            for (int t = 0; t < 16; ++t) dst[t * 64 + e4] = r0[t];
        } else if (g == 1) {
#pragma unroll
            for (int t = 0; t < 16; ++t) dst[t * 64 + 16 + e4] = r1[t];
        } else if (g == 2) {
#pragma unroll
            for (int t = 0; t < 16; ++t) dst[t * 64 + 32 + e4] = r2[t];
        } else {
#pragma unroll
            for (int t = 0; t < 16; ++t) dst[t * 64 + 48 + e4] = r3[t];
        }
    }
    __syncthreads();
#pragma unroll
    for (int q = 0; q < 4; ++q) {
        int pair = tid + q * 256;
        logits[pair] = lp[0 * 1024 + pair] + lp[1 * 1024 + pair] +
                       lp[2 * 1024 + pair] + lp[3 * 1024 + pair];
    }
    __syncthreads();
    if (tid < TB2) {
        const float* lg = &logits[tid * 64];
        float v0 = -1e30f; int i0 = 0;
        for (int q = 0; q < 64; ++q) { float v = lg[q]; if (v > v0) { v0 = v; i0 = q; } }
        float v1 = -1e30f; int i1 = 0;
        for (int q = 0; q < 64; ++q) { if (q == i0) continue; float v = lg[q]; if (v > v1) { v1 = v; i1 = q; } }
        float r = expf(v1 - v0);
        float inv = 1.f / (1.f + r);
        seli[tid * 2] = i0; seli[tid * 2 + 1] = i1;
        selp[tid * 2] = inv; selp[tid * 2 + 1] = r * inv;
    }
    __syncthreads();

    // ---- down experts: per-wave MFMA, no barriers ----
    const float sc_dn = scale_dn[0];
    const int wv = tid >> 6;
    const int lane = tid & 63;
    const int m = lane & 15, quad = lane >> 4;
    short* wtw = &wt[wv][0]; // [32 p][72 i] bf16

    const f4v zf = {0.f, 0.f, 0.f, 0.f};

#pragma unroll 1
    for (int tt = 0; tt < 4; ++tt) {
        const int t = wv * 4 + tt;
        const long long tok = tokbase + t;
        const float* xrow = h + tok * 4096; // X[64 i][64 j], j contiguous

        s8v xf[8];
#pragma unroll
        for (int mt = 0; mt < 4; ++mt)
#pragma unroll
            for (int ks = 0; ks < 2; ++ks) {
                int base = (mt * 16 + m) * 64 + ks * 32 + quad * 8;
                xf[mt * 2 + ks] = pack8(ldg4(xrow + base), ldg4(xrow + base + 4));
            }

        f4v y00 = zf, y01 = zf, y10 = zf, y11 = zf;

        for (int ke = 0; ke < 2; ++ke) {
            const int ex = seli[t * 2 + ke];
            const float pw = selp[t * 2 + ke];
            const float* A = Adn + ex * 2048; // [32 o][64 i]
            const float* B = Bdn + ex * 2048; // [32 p][64 j]

            // ---- stage 1: W[i][p] = sum_j X[i][j] * B[p][j] ----
            f4v wd[8];
#pragma unroll
            for (int ks = 0; ks < 2; ++ks) {
                s8v bf0, bf1;
                {
                    int base = (0 * 16 + m) * 64 + ks * 32 + quad * 8;
                    bf0 = pack8(ldg4(B + base), ldg4(B + base + 4));
                    base = (1 * 16 + m) * 64 + ks * 32 + quad * 8;
                    bf1 = pack8(ldg4(B + base), ldg4(B + base + 4));
                }
#pragma unroll
                for (int mt = 0; mt < 4; ++mt) {
                    wd[mt * 2 + 0] = __builtin_amdgcn_mfma_f32_16x16x32_bf16(
                        xf[mt * 2 + ks], bf0, ks == 0 ? zf : wd[mt * 2 + 0], 0, 0, 0);
                    wd[mt * 2 + 1] = __builtin_amdgcn_mfma_f32_16x16x32_bf16(
                        xf[mt * 2 + ks], bf1, ks == 0 ? zf : wd[mt * 2 + 1], 0, 0, 0);
                }
            }
#pragma unroll
            for (int mt = 0; mt < 4; ++mt)
#pragma unroll
                for (int pt = 0; pt < 2; ++pt) {
                    f4v w = wd[mt * 2 + pt];
                    s4v s;
                    s[0] = f2b(w[0] * pw); s[1] = f2b(w[1] * pw);
                    s[2] = f2b(w[2] * pw); s[3] = f2b(w[3] * pw);
                    *(s4v*)&wtw[(pt * 16 + m) * 72 + mt * 16 + quad * 4] = s;
                }

            // ---- stage 2: Y[o][p] += sum_i A[o][i] * (pw*W)[i][p] ----
#pragma unroll
            for (int ks = 0; ks < 2; ++ks) {
                s8v wb0 = *(s8v*)&wtw[(0 * 16 + m) * 72 + ks * 32 + quad * 8];
                s8v wb1 = *(s8v*)&wtw[(1 * 16 + m) * 72 + ks * 32 + quad * 8];
                s8v af0, af1;
                {
                    int base = (0 * 16 + m) * 64 + ks * 32 + quad * 8;
                    af0 = pack8(ldg4(A + base), ldg4(A + base + 4));
                    base = (1 * 16 + m) * 64 + ks * 32 + quad * 8;
                    af1 = pack8(ldg4(A + base), ldg4(A + base + 4));
                }
                y00 = __builtin_amdgcn_mfma_f32_16x16x32_bf16(af0, wb0, y00, 0, 0, 0);
                y01 = __builtin_amdgcn_mfma_f32_16x16x32_bf16(af0, wb1, y01, 0, 0, 0);
                y10 = __builtin_amdgcn_mfma_f32_16x16x32_bf16(af1, wb0, y10, 0, 0, 0);
                y11 = __builtin_amdgcn_mfma_f32_16x16x32_bf16(af1, wb1, y11, 0, 0, 0);
            }
        }

        float* orow = out + tok * 1024;
#pragma unroll
        for (int r = 0; r < 4; ++r) {
            int o0 = quad * 4 + r;
            int f00 = o0 * 32 + m;
            orow[f00]            = y00[r] * sc_dn + bias_dn[f00];
            orow[f00 + 16]       = y01[r] * sc_dn + bias_dn[f00 + 16];
            int f10 = (o0 + 16) * 32 + m;
            orow[f10]            = y10[r] * sc_dn + bias_dn[f10];
            orow[f10 + 16]       = y11[r] * sc_dn + bias_dn[f10 + 16];
        }
    }
}

extern "C" void kernel_launch(void* const* d_in, const int* in_sizes, int n_in,
                              void* d_out, int out_size, void* d_ws, size_t ws_size,
                              hipStream_t stream) {
    const float* x   = (const float*)d_in[0];
    const float* Wup = (const float*)d_in[1];
    const float* Aup = (const float*)d_in[2];
    const float* Bup = (const float*)d_in[3];
    const float* scu = (const float*)d_in[4];
    const float* biu = (const float*)d_in[5];
    const float* Wdn = (const float*)d_in[6];
    const float* Adn = (const float*)d_in[7];
    const float* Bdn = (const float*)d_in[8];
    const float* scd = (const float*)d_in[9];
    const float* bid = (const float*)d_in[10];
    float* out = (float*)d_out;
    float* h   = (float*)d_ws;   // [N][4096] fp32 = 128 MB for N=8192

    const int N = in_sizes[0] / 1024;

    hipLaunchKernelGGL(up_kernel, dim3(N / TB1), dim3(256), 0, stream,
                       x, Wup, Aup, Bup, scu, biu, h);
    hipLaunchKernelGGL(down_kernel, dim3(N / TB2), dim3(256), 0, stream,
                       h, Wdn, Adn, Bdn, scd, bid, out);
}

// Round 6
// 389.487 us; speedup vs baseline: 9.1960x; 1.3089x over previous
//
#include <hip/hip_runtime.h>
#include <math.h>

#define TB1 4
#define TB2 16

typedef __attribute__((ext_vector_type(8))) short s8v;
typedef __attribute__((ext_vector_type(4))) short s4v;
typedef __attribute__((ext_vector_type(4))) float f4v;

__device__ __forceinline__ float4 ldg4(const float* p) { return *(const float4*)p; }

// fp32 -> bf16 round-to-nearest-even
__device__ __forceinline__ short f2b(float f) {
    union { float f; unsigned u; } v; v.f = f;
    unsigned r = v.u + 0x7fffu + ((v.u >> 16) & 1u);
    return (short)(r >> 16);
}
__device__ __forceinline__ s8v pack8(float4 a, float4 b) {
    s8v r;
    r[0] = f2b(a.x); r[1] = f2b(a.y); r[2] = f2b(a.z); r[3] = f2b(a.w);
    r[4] = f2b(b.x); r[5] = f2b(b.y); r[6] = f2b(b.z); r[7] = f2b(b.w);
    return r;
}

// ---------------------------------------------------------------------------
// Kernel 1: up router + up experts + gelu -> h (fp32 [N][4096])
// R0-verified arithmetic, bitwise identical h. Only change: T14 async-STAGE
// split — global loads for iteration k+1 issue into registers before the
// compute of iteration k; the LDS write happens at the top of k+1. Staging
// values, LDS layout, and barrier structure are unchanged.
// ---------------------------------------------------------------------------
__global__ __launch_bounds__(256, 3) void up_kernel(
    const float* __restrict__ x, const float* __restrict__ Wup,
    const float* __restrict__ Aup, const float* __restrict__ Bup,
    const float* __restrict__ scale_up, const float* __restrict__ bias_up,
    float* __restrict__ h)
{
    __shared__ __align__(16) float xs[TB1 * 1024];
    __shared__ __align__(16) float buf[6912];
    __shared__ __align__(16) float lp[4 * TB1 * 64];
    __shared__ __align__(16) float logits[TB1 * 64];
    __shared__ int   seli[TB1 * 2];
    __shared__ float selp[TB1 * 2];

    const int tid = threadIdx.x;
    const long long blockTok = (long long)blockIdx.x * TB1;

    // ---- stage x rows (verbatim) ----
    {
        const float* src = x + blockTok * 1024;
#pragma unroll
        for (int q = 0; q < TB1; ++q) {
            int flat = tid * 4 + q * 1024;
            *(float4*)&xs[flat] = ldg4(src + flat);
        }
    }

    // ---- router: logits = x . Wup^T (bitwise-identical; staged via regs) ----
    float racc0[TB1] = {0.f, 0.f, 0.f, 0.f};
    float racc1[TB1] = {0.f, 0.f, 0.f, 0.f};
    float* wcs = buf;
    const int e2 = tid & 31, jsl = tid >> 5;
    const int prow = tid >> 4, pcol = (tid & 15) * 4;

    float4 qw0 = ldg4(&Wup[(prow +  0) * 1024 + 0 + pcol]);
    float4 qw1 = ldg4(&Wup[(prow + 16) * 1024 + 0 + pcol]);
    float4 qw2 = ldg4(&Wup[(prow + 32) * 1024 + 0 + pcol]);
    float4 qw3 = ldg4(&Wup[(prow + 48) * 1024 + 0 + pcol]);

    for (int kc = 0; kc < 1024; kc += 64) {
        __syncthreads();
        *(float4*)&wcs[(prow +  0) * 68 + pcol] = qw0;
        *(float4*)&wcs[(prow + 16) * 68 + pcol] = qw1;
        *(float4*)&wcs[(prow + 32) * 68 + pcol] = qw2;
        *(float4*)&wcs[(prow + 48) * 68 + pcol] = qw3;
        {
            int nkc = (kc + 64 < 1024) ? kc + 64 : 0;  // last prefetch discarded
            qw0 = ldg4(&Wup[(prow +  0) * 1024 + nkc + pcol]);
            qw1 = ldg4(&Wup[(prow + 16) * 1024 + nkc + pcol]);
            qw2 = ldg4(&Wup[(prow + 32) * 1024 + nkc + pcol]);
            qw3 = ldg4(&Wup[(prow + 48) * 1024 + nkc + pcol]);
        }
        __syncthreads();
#pragma unroll
        for (int ks = 0; ks < 2; ++ks) {
            int kk = jsl * 8 + ks * 4;
            float4 w0 = *(float4*)&wcs[e2 * 68 + kk];
            float4 w1 = *(float4*)&wcs[(e2 + 32) * 68 + kk];
#pragma unroll
            for (int t = 0; t < TB1; ++t) {
                float4 xv = *(float4*)&xs[t * 1024 + kc + kk];
                racc0[t] += w0.x * xv.x + w0.y * xv.y + w0.z * xv.z + w0.w * xv.w;
                racc1[t] += w1.x * xv.x + w1.y * xv.y + w1.z * xv.z + w1.w * xv.w;
            }
        }
    }
#pragma unroll
    for (int t = 0; t < TB1; ++t) {
        racc0[t] += __shfl_xor(racc0[t], 32);
        racc1[t] += __shfl_xor(racc1[t], 32);
    }
    {
        const int wv = tid >> 6;
        if ((tid & 32) == 0) {
#pragma unroll
            for (int t = 0; t < TB1; ++t) {
                lp[(wv * TB1 + t) * 64 + e2]      = racc0[t];
                lp[(wv * TB1 + t) * 64 + e2 + 32] = racc1[t];
            }
        }
    }
    __syncthreads();
    logits[tid] = lp[0 * 256 + tid] + lp[1 * 256 + tid] + lp[2 * 256 + tid] + lp[3 * 256 + tid];
    __syncthreads();
    if (tid < TB1) {
        const float* lg = &logits[tid * 64];
        float v0 = -1e30f; int i0 = 0;
        for (int q = 0; q < 64; ++q) { float v = lg[q]; if (v > v0) { v0 = v; i0 = q; } }
        float v1 = -1e30f; int i1 = 0;
        for (int q = 0; q < 64; ++q) { if (q == i0) continue; float v = lg[q]; if (v > v1) { v1 = v; i1 = q; } }
        float r = expf(v1 - v0);
        float inv = 1.f / (1.f + r);
        seli[tid * 2] = i0; seli[tid * 2 + 1] = i1;
        selp[tid * 2] = inv; selp[tid * 2 + 1] = r * inv;
    }
    __syncthreads();

    // ---- experts (verbatim arithmetic; A/B staged via register prefetch) ----
    float* as_ = buf;
    float* bs_ = buf + 2304;
    float* t1_ = buf + 4608;
    const float sc_up = scale_up[0];

    const int flat0 = tid * 4, flat1 = tid * 4 + 1024;
    const int r0_ = flat0 >> 5, c0_ = flat0 & 31;
    const int r1_ = flat1 >> 5, c1_ = flat1 & 31;

    float4 rA0, rA1, rB0, rB1;
    {
        const float* A = Aup + seli[0] * 2048;
        const float* B = Bup + seli[0] * 2048;
        rA0 = ldg4(A + flat0); rA1 = ldg4(A + flat1);
        rB0 = ldg4(B + flat0); rB1 = ldg4(B + flat1);
    }

    for (int t = 0; t < TB1; ++t) {
        float acc[16];
#pragma unroll
        for (int q = 0; q < 16; ++q) acc[q] = 0.f;

        for (int ke = 0; ke < 2; ++ke) {
            __syncthreads();
            float pw = selp[t * 2 + ke];
            {
                // write current iteration's staging (identical values/layout)
                *(float4*)&as_[r0_ * 36 + c0_] = rA0;
                *(float4*)&as_[r1_ * 36 + c1_] = rA1;
                float4 bv0 = rB0, bv1 = rB1;
                bv0.x *= pw; bv0.y *= pw; bv0.z *= pw; bv0.w *= pw;
                bv1.x *= pw; bv1.y *= pw; bv1.z *= pw; bv1.w *= pw;
                *(float4*)&bs_[r0_ * 36 + c0_] = bv0;
                *(float4*)&bs_[r1_ * 36 + c1_] = bv1;
            }
            {
                // issue next iteration's loads (hidden under compute below)
                int nit = t * 2 + ke + 1; if (nit > 7) nit = 7;  // final reload discarded
                const float* An = Aup + seli[nit] * 2048;
                const float* Bn = Bup + seli[nit] * 2048;
                rA0 = ldg4(An + flat0); rA1 = ldg4(An + flat1);
                rB0 = ldg4(Bn + flat0); rB1 = ldg4(Bn + flat1);
            }
            __syncthreads();
            {
                int og = tid >> 3, j0 = (tid & 7) * 4;
                float4 s0 = make_float4(0.f, 0.f, 0.f, 0.f);
                float4 s1 = make_float4(0.f, 0.f, 0.f, 0.f);
#pragma unroll 8
                for (int i = 0; i < 32; ++i) {
                    float a0 = as_[og * 36 + i];
                    float a1 = as_[(og + 32) * 36 + i];
                    float4 xv = *(float4*)&xs[t * 1024 + i * 32 + j0];
                    s0.x += a0 * xv.x; s0.y += a0 * xv.y; s0.z += a0 * xv.z; s0.w += a0 * xv.w;
                    s1.x += a1 * xv.x; s1.y += a1 * xv.y; s1.z += a1 * xv.z; s1.w += a1 * xv.w;
                }
                *(float4*)&t1_[og * 36 + j0] = s0;
                *(float4*)&t1_[(og + 32) * 36 + j0] = s1;
            }
            __syncthreads();
            {
                int o0 = tid >> 4, p0 = tid & 15;
#pragma unroll 1
                for (int jq = 0; jq < 8; ++jq) {
                    int j = jq * 4;
                    float4 t0 = *(float4*)&t1_[o0 * 36 + j];
                    float4 t1v = *(float4*)&t1_[(o0 + 16) * 36 + j];
                    float4 t2 = *(float4*)&t1_[(o0 + 32) * 36 + j];
                    float4 t3 = *(float4*)&t1_[(o0 + 48) * 36 + j];
#pragma unroll
                    for (int b = 0; b < 4; ++b) {
                        float4 bv = *(float4*)&bs_[(p0 + 16 * b) * 36 + j];
                        acc[0 * 4 + b] += t0.x * bv.x + t0.y * bv.y + t0.z * bv.z + t0.w * bv.w;
                        acc[1 * 4 + b] += t1v.x * bv.x + t1v.y * bv.y + t1v.z * bv.z + t1v.w * bv.w;
                        acc[2 * 4 + b] += t2.x * bv.x + t2.y * bv.y + t2.z * bv.z + t2.w * bv.w;
                        acc[3 * 4 + b] += t3.x * bv.x + t3.y * bv.y + t3.z * bv.z + t3.w * bv.w;
                    }
                }
            }
        }
        __syncthreads();
        {
            float* yl = buf;
            int o0 = tid >> 4, p0 = tid & 15;
#pragma unroll
            for (int a = 0; a < 4; ++a)
#pragma unroll
                for (int b = 0; b < 4; ++b)
                    yl[(o0 + 16 * a) * 68 + (p0 + 16 * b)] = acc[a * 4 + b] * sc_up;
        }
        __syncthreads();
        {
            long long tok = blockTok + t;
            float* hrow = h + tok * 4096;
            float* yl = buf;
#pragma unroll
            for (int q = 0; q < 4; ++q) {
                int f = q * 1024 + tid * 4;
                int o = f >> 6, p = f & 63;
                float4 v = *(float4*)&yl[o * 68 + p];
                float4 bb = ldg4(&bias_up[f]);
                float4 g;
                float z;
                z = v.x + bb.x; g.x = 0.5f * z * (1.0f + erff(z * 0.70710678118654752f));
                z = v.y + bb.y; g.y = 0.5f * z * (1.0f + erff(z * 0.70710678118654752f));
                z = v.z + bb.z; g.z = 0.5f * z * (1.0f + erff(z * 0.70710678118654752f));
                z = v.w + bb.w; g.w = 0.5f * z * (1.0f + erff(z * 0.70710678118654752f));
                *(float4*)&hrow[f] = g;
            }
        }
    }
}

// ---------------------------------------------------------------------------
// Kernel 2: down router + down experts (bf16 MFMA, per-wave).
// R0-verified arithmetic, bitwise identical out. Changes: (a) T14 register
// prefetch of Wdn/h staging chunks; (b) expert-phase wt aliased over the
// dead router LDS (60.2KB -> 42.5KB) + launch_bounds(256,3) for 3 blocks/CU.
// All barriers/values/layout otherwise unchanged.
// ---------------------------------------------------------------------------
__global__ __launch_bounds__(256, 3) void down_kernel(
    const float* __restrict__ h,        // [N][4096]
    const float* __restrict__ Wdn,      // [64][4096]
    const float* __restrict__ Adn,      // [64][32][64]
    const float* __restrict__ Bdn,      // [64][32][64]
    const float* __restrict__ scale_dn, // [1]
    const float* __restrict__ bias_dn,  // [1024]
    float* __restrict__ out)            // [N][1024]
{
    // wcs [64][68] (17408B) | hcs [16][68] (4352B) | lp [4][16][64] (16384B)
    // | logits [16][64] (4096B)  = 42240B.  wt (18432B) aliases wcs+hcs,
    // both dead after the lp-write barrier.
    __shared__ __align__(16) char smem[42240];
    float* wcs    = (float*)smem;
    float* hcs    = (float*)(smem + 17408);
    float* lp     = (float*)(smem + 21760);
    float* logits = (float*)(smem + 38144);
    short* wt     = (short*)smem;
    __shared__ int   seli[TB2 * 2];
    __shared__ float selp[TB2 * 2];

    const int tid = threadIdx.x;
    const long long tokbase = (long long)blockIdx.x * TB2;

    // ---- down router: 4 experts per thread, k-slice = one float4 ----
    const int e4 = tid & 15, jsl = tid >> 4; // jsl 0..15
    float r0[16], r1[16], r2[16], r3[16];
#pragma unroll
    for (int t = 0; t < 16; ++t) { r0[t] = 0.f; r1[t] = 0.f; r2[t] = 0.f; r3[t] = 0.f; }

    const int prow = tid >> 4, pcol = (tid & 15) * 4;
    float4 qw0 = ldg4(&Wdn[(prow +  0) * 4096 + 0 + pcol]);
    float4 qw1 = ldg4(&Wdn[(prow + 16) * 4096 + 0 + pcol]);
    float4 qw2 = ldg4(&Wdn[(prow + 32) * 4096 + 0 + pcol]);
    float4 qw3 = ldg4(&Wdn[(prow + 48) * 4096 + 0 + pcol]);
    float4 qh  = ldg4(&h[(tokbase + prow) * 4096 + 0 + pcol]);

    for (int kc = 0; kc < 4096; kc += 64) {
        __syncthreads();
        *(float4*)&wcs[(prow +  0) * 68 + pcol] = qw0;
        *(float4*)&wcs[(prow + 16) * 68 + pcol] = qw1;
        *(float4*)&wcs[(prow + 32) * 68 + pcol] = qw2;
        *(float4*)&wcs[(prow + 48) * 68 + pcol] = qw3;
        *(float4*)&hcs[prow * 68 + pcol] = qh;
        {
            int nkc = (kc + 64 < 4096) ? kc + 64 : 0;  // last prefetch discarded
            qw0 = ldg4(&Wdn[(prow +  0) * 4096 + nkc + pcol]);
            qw1 = ldg4(&Wdn[(prow + 16) * 4096 + nkc + pcol]);
            qw2 = ldg4(&Wdn[(prow + 32) * 4096 + nkc + pcol]);
            qw3 = ldg4(&Wdn[(prow + 48) * 4096 + nkc + pcol]);
            qh  = ldg4(&h[(tokbase + prow) * 4096 + nkc + pcol]);
        }
        __syncthreads();
        const int kk = jsl * 4;
        float4 w0 = *(float4*)&wcs[(e4)      * 68 + kk];
        float4 w1 = *(float4*)&wcs[(e4 + 16) * 68 + kk];
        float4 w2 = *(float4*)&wcs[(e4 + 32) * 68 + kk];
        float4 w3 = *(float4*)&wcs[(e4 + 48) * 68 + kk];
#pragma unroll
        for (int t = 0; t < 16; ++t) {
            float4 hv = *(float4*)&hcs[t * 68 + kk];
            r0[t] += w0.x * hv.x + w0.y * hv.y + w0.z * hv.z + w0.w * hv.w;
            r1[t] += w1.x * hv.x + w1.y * hv.y + w1.z * hv.z + w1.w * hv.w;
            r2[t] += w2.x * hv.x + w2.y * hv.y + w2.z * hv.z + w2.w * hv.w;
            r3[t] += w3.x * hv.x + w3.y * hv.y + w3.z * hv.z + w3.w * hv.w;
        }
    }
    // reduce over the wave's 4 k-slices (lanes xor 16, 32)
#pragma unroll
    for (int t = 0; t < 16; ++t) {
        r0[t] += __shfl_xor(r0[t], 16); r0[t] += __shfl_xor(r0[t], 32);
        r1[t] += __shfl_xor(r1[t], 16); r1[t] += __shfl_xor(r1[t], 32);
        r2[t] += __shfl_xor(r2[t], 16); r2[t] += __shfl_xor(r2[t], 32);
        r3[t] += __shfl_xor(r3[t], 16); r3[t] += __shfl_xor(r3[t], 32);
    }
    {
        const int wv = tid >> 6, g = (tid >> 4) & 3;
        float* dst = &lp[wv * 1024];
        if (g == 0) {
#pragma unroll
            for (int t = 0; t < 16; ++t) dst[t * 64 + e4] = r0[t];
        } else if (g == 1) {
#pragma unroll
            for (int t = 0; t < 16; ++t) dst[t * 64 + 16 + e4] = r1[t];
        } else if (g == 2) {
#pragma unroll
            for (int t = 0; t < 16; ++t) dst[t * 64 + 32 + e4] = r2[t];
        } else {
#pragma unroll
            for (int t = 0; t < 16; ++t) dst[t * 64 + 48 + e4] = r3[t];
        }
    }
    __syncthreads();
#pragma unroll
    for (int q = 0; q < 4; ++q) {
        int pair = tid + q * 256;
        logits[pair] = lp[0 * 1024 + pair] + lp[1 * 1024 + pair] +
                       lp[2 * 1024 + pair] + lp[3 * 1024 + pair];
    }
    __syncthreads();
    if (tid < TB2) {
        const float* lg = &logits[tid * 64];
        float v0 = -1e30f; int i0 = 0;
        for (int q = 0; q < 64; ++q) { float v = lg[q]; if (v > v0) { v0 = v; i0 = q; } }
        float v1 = -1e30f; int i1 = 0;
        for (int q = 0; q < 64; ++q) { if (q == i0) continue; float v = lg[q]; if (v > v1) { v1 = v; i1 = q; } }
        float r = expf(v1 - v0);
        float inv = 1.f / (1.f + r);
        seli[tid * 2] = i0; seli[tid * 2 + 1] = i1;
        selp[tid * 2] = inv; selp[tid * 2 + 1] = r * inv;
    }
    __syncthreads();   // router LDS dead past here; wt aliases it

    // ---- down experts: per-wave MFMA, no barriers (verbatim) ----
    const float sc_dn = scale_dn[0];
    const int wv = tid >> 6;
    const int lane = tid & 63;
    const int m = lane & 15, quad = lane >> 4;
    short* wtw = wt + wv * 2304; // [32 p][72 i] bf16 per wave

    const f4v zf = {0.f, 0.f, 0.f, 0.f};

#pragma unroll 1
    for (int tt = 0; tt < 4; ++tt) {
        const int t = wv * 4 + tt;
        const long long tok = tokbase + t;
        const float* xrow = h + tok * 4096; // X[64 i][64 j], j contiguous

        s8v xf[8];
#pragma unroll
        for (int mt = 0; mt < 4; ++mt)
#pragma unroll
            for (int ks = 0; ks < 2; ++ks) {
                int base = (mt * 16 + m) * 64 + ks * 32 + quad * 8;
                xf[mt * 2 + ks] = pack8(ldg4(xrow + base), ldg4(xrow + base + 4));
            }

        f4v y00 = zf, y01 = zf, y10 = zf, y11 = zf;

        for (int ke = 0; ke < 2; ++ke) {
            const int ex = seli[t * 2 + ke];
            const float pw = selp[t * 2 + ke];
            const float* A = Adn + ex * 2048; // [32 o][64 i]
            const float* B = Bdn + ex * 2048; // [32 p][64 j]

            // ---- stage 1: W[i][p] = sum_j X[i][j] * B[p][j] ----
            f4v wd[8];
#pragma unroll
            for (int ks = 0; ks < 2; ++ks) {
                s8v bf0, bf1;
                {
                    int base = (0 * 16 + m) * 64 + ks * 32 + quad * 8;
                    bf0 = pack8(ldg4(B + base), ldg4(B + base + 4));
                    base = (1 * 16 + m) * 64 + ks * 32 + quad * 8;
                    bf1 = pack8(ldg4(B + base), ldg4(B + base + 4));
                }
#pragma unroll
                for (int mt = 0; mt < 4; ++mt) {
                    wd[mt * 2 + 0] = __builtin_amdgcn_mfma_f32_16x16x32_bf16(
                        xf[mt * 2 + ks], bf0, ks == 0 ? zf : wd[mt * 2 + 0], 0, 0, 0);
                    wd[mt * 2 + 1] = __builtin_amdgcn_mfma_f32_16x16x32_bf16(
                        xf[mt * 2 + ks], bf1, ks == 0 ? zf : wd[mt * 2 + 1], 0, 0, 0);
                }
            }
#pragma unroll
            for (int mt = 0; mt < 4; ++mt)
#pragma unroll
                for (int pt = 0; pt < 2; ++pt) {
                    f4v w = wd[mt * 2 + pt];
                    s4v s;
                    s[0] = f2b(w[0] * pw); s[1] = f2b(w[1] * pw);
                    s[2] = f2b(w[2] * pw); s[3] = f2b(w[3] * pw);
                    *(s4v*)&wtw[(pt * 16 + m) * 72 + mt * 16 + quad * 4] = s;
                }

            // ---- stage 2: Y[o][p] += sum_i A[o][i] * (pw*W)[i][p] ----
#pragma unroll
            for (int ks = 0; ks < 2; ++ks) {
                s8v wb0 = *(s8v*)&wtw[(0 * 16 + m) * 72 + ks * 32 + quad * 8];
                s8v wb1 = *(s8v*)&wtw[(1 * 16 + m) * 72 + ks * 32 + quad * 8];
                s8v af0, af1;
                {
                    int base = (0 * 16 + m) * 64 + ks * 32 + quad * 8;
                    af0 = pack8(ldg4(A + base), ldg4(A + base + 4));
                    base = (1 * 16 + m) * 64 + ks * 32 + quad * 8;
                    af1 = pack8(ldg4(A + base), ldg4(A + base + 4));
                }
                y00 = __builtin_amdgcn_mfma_f32_16x16x32_bf16(af0, wb0, y00, 0, 0, 0);
                y01 = __builtin_amdgcn_mfma_f32_16x16x32_bf16(af0, wb1, y01, 0, 0, 0);
                y10 = __builtin_amdgcn_mfma_f32_16x16x32_bf16(af1, wb0, y10, 0, 0, 0);
                y11 = __builtin_amdgcn_mfma_f32_16x16x32_bf16(af1, wb1, y11, 0, 0, 0);
            }
        }

        float* orow = out + tok * 1024;
#pragma unroll
        for (int r = 0; r < 4; ++r) {
            int o0 = quad * 4 + r;
            int f00 = o0 * 32 + m;
            orow[f00]            = y00[r] * sc_dn + bias_dn[f00];
            orow[f00 + 16]       = y01[r] * sc_dn + bias_dn[f00 + 16];
            int f10 = (o0 + 16) * 32 + m;
            orow[f10]            = y10[r] * sc_dn + bias_dn[f10];
            orow[f10 + 16]       = y11[r] * sc_dn + bias_dn[f10 + 16];
        }
    }
}

extern "C" void kernel_launch(void* const* d_in, const int* in_sizes, int n_in,
                              void* d_out, int out_size, void* d_ws, size_t ws_size,
                              hipStream_t stream) {
    const float* x   = (const float*)d_in[0];
    const float* Wup = (const float*)d_in[1];
    const float* Aup = (const float*)d_in[2];
    const float* Bup = (const float*)d_in[3];
    const float* scu = (const float*)d_in[4];
    const float* biu = (const float*)d_in[5];
    const float* Wdn = (const float*)d_in[6];
    const float* Adn = (const float*)d_in[7];
    const float* Bdn = (const float*)d_in[8];
    const float* scd = (const float*)d_in[9];
    const float* bid = (const float*)d_in[10];
    float* out = (float*)d_out;
    float* h   = (float*)d_ws;   // [N][4096] fp32 = 128 MB for N=8192

    const int N = in_sizes[0] / 1024;

    hipLaunchKernelGGL(up_kernel, dim3(N / TB1), dim3(256), 0, stream,
                       x, Wup, Aup, Bup, scu, biu, h);
    hipLaunchKernelGGL(down_kernel, dim3(N / TB2), dim3(256), 0, stream,
                       h, Wdn, Adn, Bdn, scd, bid, out);
}

// Round 7
// 379.764 us; speedup vs baseline: 9.4315x; 1.0256x over previous
//
#include <hip/hip_runtime.h>
#include <math.h>

#define TB1 4
#define TB2 16

typedef __attribute__((ext_vector_type(8))) short s8v;
typedef __attribute__((ext_vector_type(4))) short s4v;
typedef __attribute__((ext_vector_type(4))) float f4v;

__device__ __forceinline__ float4 ldg4(const float* p) { return *(const float4*)p; }

// fp32 -> bf16 round-to-nearest-even
__device__ __forceinline__ short f2b(float f) {
    union { float f; unsigned u; } v; v.f = f;
    unsigned r = v.u + 0x7fffu + ((v.u >> 16) & 1u);
    return (short)(r >> 16);
}
__device__ __forceinline__ float b2f(short s) {
    union { unsigned u; float f; } v; v.u = ((unsigned)(unsigned short)s) << 16;
    return v.f;
}
__device__ __forceinline__ s8v pack8(float4 a, float4 b) {
    s8v r;
    r[0] = f2b(a.x); r[1] = f2b(a.y); r[2] = f2b(a.z); r[3] = f2b(a.w);
    r[4] = f2b(b.x); r[5] = f2b(b.y); r[6] = f2b(b.z); r[7] = f2b(b.w);
    return r;
}

// bf16x3 split of 8 fp32 (Ootomo-style): v = hi + mid + lo, each bf16.
struct S3 { s8v h, m, l; };
__device__ __forceinline__ S3 split8(f4v a, f4v b) {
    S3 o;
#pragma unroll
    for (int u = 0; u < 4; ++u) {
        float v = a[u];
        short sh = f2b(v); float r  = v - b2f(sh);
        short sm = f2b(r); float r2 = r - b2f(sm);
        o.h[u] = sh; o.m[u] = sm; o.l[u] = f2b(r2);
        v = b[u];
        sh = f2b(v); r  = v - b2f(sh);
        sm = f2b(r); r2 = r - b2f(sm);
        o.h[u + 4] = sh; o.m[u + 4] = sm; o.l[u + 4] = f2b(r2);
    }
    return o;
}

// 6-term bf16x3 product-sum (small terms first): rel err ~6e-8
__device__ __forceinline__ f4v mfma6(const S3& A, const S3& B, f4v acc) {
    acc = __builtin_amdgcn_mfma_f32_16x16x32_bf16(A.l, B.h, acc, 0, 0, 0);
    acc = __builtin_amdgcn_mfma_f32_16x16x32_bf16(A.m, B.m, acc, 0, 0, 0);
    acc = __builtin_amdgcn_mfma_f32_16x16x32_bf16(A.h, B.l, acc, 0, 0, 0);
    acc = __builtin_amdgcn_mfma_f32_16x16x32_bf16(A.m, B.h, acc, 0, 0, 0);
    acc = __builtin_amdgcn_mfma_f32_16x16x32_bf16(A.h, B.m, acc, 0, 0, 0);
    acc = __builtin_amdgcn_mfma_f32_16x16x32_bf16(A.h, B.h, acc, 0, 0, 0);
    return acc;
}

// ---------------------------------------------------------------------------
// Kernel 1: up router (R6-verbatim, bitwise logits) + bf16x3-MFMA experts +
// gelu. Expert phase per wave (1 token/wave, no barriers):
//   stage1 W[i][p] = X.B^T via 6-term bf16x3 MFMA (layout proven in R1/R2
//   forensics); W*pw -> fp32 LDS [64 p][36-stride i] (aliased over dead
//   router LDS); stage2 Y[o][p] = A.W via 6-term bf16x3 MFMA; gelu epilogue
//   stores h directly. h rel err ~1.5e-7 (reorder-class; R4/R6 proved the
//   down router tolerates this; bf16's 3e-3 was the failure mode).
// ---------------------------------------------------------------------------
__global__ __launch_bounds__(256, 3) void up_kernel(
    const float* __restrict__ x, const float* __restrict__ Wup,
    const float* __restrict__ Aup, const float* __restrict__ Bup,
    const float* __restrict__ scale_up, const float* __restrict__ bias_up,
    float* __restrict__ h)
{
    // router: xs@0 (16384B) | wcs@16384 (17408B) | lp@33792 (4096B) |
    //         logits@37888 (1024B)  = 38912B
    // expert: wt@0 = [4 waves][64 p][36 i] fp32 (36864B) aliases xs..lp.
    __shared__ __align__(16) char smem[38912];
    float* xs     = (float*)smem;
    float* wcs    = (float*)(smem + 16384);
    float* lp     = (float*)(smem + 33792);
    float* logits = (float*)(smem + 37888);
    float* wt     = (float*)smem;
    __shared__ int   seli[TB1 * 2];
    __shared__ float selp[TB1 * 2];

    const int tid = threadIdx.x;
    const long long blockTok = (long long)blockIdx.x * TB1;

    // ---- stage x rows (verbatim) ----
    {
        const float* src = x + blockTok * 1024;
#pragma unroll
        for (int q = 0; q < TB1; ++q) {
            int flat = tid * 4 + q * 1024;
            *(float4*)&xs[flat] = ldg4(src + flat);
        }
    }

    // ---- router: logits = x . Wup^T (R6-verbatim, bitwise; T14 prefetch) ----
    float racc0[TB1] = {0.f, 0.f, 0.f, 0.f};
    float racc1[TB1] = {0.f, 0.f, 0.f, 0.f};
    const int e2 = tid & 31, jsl = tid >> 5;
    const int prow = tid >> 4, pcol = (tid & 15) * 4;

    float4 qw0 = ldg4(&Wup[(prow +  0) * 1024 + 0 + pcol]);
    float4 qw1 = ldg4(&Wup[(prow + 16) * 1024 + 0 + pcol]);
    float4 qw2 = ldg4(&Wup[(prow + 32) * 1024 + 0 + pcol]);
    float4 qw3 = ldg4(&Wup[(prow + 48) * 1024 + 0 + pcol]);

    for (int kc = 0; kc < 1024; kc += 64) {
        __syncthreads();
        *(float4*)&wcs[(prow +  0) * 68 + pcol] = qw0;
        *(float4*)&wcs[(prow + 16) * 68 + pcol] = qw1;
        *(float4*)&wcs[(prow + 32) * 68 + pcol] = qw2;
        *(float4*)&wcs[(prow + 48) * 68 + pcol] = qw3;
        {
            int nkc = (kc + 64 < 1024) ? kc + 64 : 0;  // last prefetch discarded
            qw0 = ldg4(&Wup[(prow +  0) * 1024 + nkc + pcol]);
            qw1 = ldg4(&Wup[(prow + 16) * 1024 + nkc + pcol]);
            qw2 = ldg4(&Wup[(prow + 32) * 1024 + nkc + pcol]);
            qw3 = ldg4(&Wup[(prow + 48) * 1024 + nkc + pcol]);
        }
        __syncthreads();
#pragma unroll
        for (int ks = 0; ks < 2; ++ks) {
            int kk = jsl * 8 + ks * 4;
            float4 w0 = *(float4*)&wcs[e2 * 68 + kk];
            float4 w1 = *(float4*)&wcs[(e2 + 32) * 68 + kk];
#pragma unroll
            for (int t = 0; t < TB1; ++t) {
                float4 xv = *(float4*)&xs[t * 1024 + kc + kk];
                racc0[t] += w0.x * xv.x + w0.y * xv.y + w0.z * xv.z + w0.w * xv.w;
                racc1[t] += w1.x * xv.x + w1.y * xv.y + w1.z * xv.z + w1.w * xv.w;
            }
        }
    }
#pragma unroll
    for (int t = 0; t < TB1; ++t) {
        racc0[t] += __shfl_xor(racc0[t], 32);
        racc1[t] += __shfl_xor(racc1[t], 32);
    }
    {
        const int wv = tid >> 6;
        if ((tid & 32) == 0) {
#pragma unroll
            for (int t = 0; t < TB1; ++t) {
                lp[(wv * TB1 + t) * 64 + e2]      = racc0[t];
                lp[(wv * TB1 + t) * 64 + e2 + 32] = racc1[t];
            }
        }
    }
    __syncthreads();
    logits[tid] = lp[0 * 256 + tid] + lp[1 * 256 + tid] + lp[2 * 256 + tid] + lp[3 * 256 + tid];
    __syncthreads();
    if (tid < TB1) {
        const float* lg = &logits[tid * 64];
        float v0 = -1e30f; int i0 = 0;
        for (int q = 0; q < 64; ++q) { float v = lg[q]; if (v > v0) { v0 = v; i0 = q; } }
        float v1 = -1e30f; int i1 = 0;
        for (int q = 0; q < 64; ++q) { if (q == i0) continue; float v = lg[q]; if (v > v1) { v1 = v; i1 = q; } }
        float r = expf(v1 - v0);
        float inv = 1.f / (1.f + r);
        seli[tid * 2] = i0; seli[tid * 2 + 1] = i1;
        selp[tid * 2] = inv; selp[tid * 2 + 1] = r * inv;
    }
    __syncthreads();

    // ---- experts: per-wave bf16x3 MFMA, 1 token/wave ----
    const float sc_up = scale_up[0];
    const int wv = tid >> 6, lane = tid & 63;
    const int m = lane & 15, quad = lane >> 4;
    const long long tok = blockTok + wv;
    float* wtw = wt + wv * 2304;     // [64 p][36 i] fp32 per wave

    // X fp32 fragments from xs (before wt aliases it):
    // frag mt: X[i = mt*16 + m][j = quad*8 .. +7]
    const float* xrow = &xs[wv * 1024];
    f4v xA0 = *(const f4v*)&xrow[(0 * 16 + m) * 32 + quad * 8];
    f4v xA1 = *(const f4v*)&xrow[(0 * 16 + m) * 32 + quad * 8 + 4];
    f4v xB0 = *(const f4v*)&xrow[(1 * 16 + m) * 32 + quad * 8];
    f4v xB1 = *(const f4v*)&xrow[(1 * 16 + m) * 32 + quad * 8 + 4];
    __syncthreads();   // xs dead; wt region free for expert phase

    const f4v zf = {0.f, 0.f, 0.f, 0.f};
    f4v Y[16];   // [ot 0..3][pt 0..3]
#pragma unroll
    for (int q = 0; q < 16; ++q) Y[q] = zf;

#pragma unroll 1
    for (int ke = 0; ke < 2; ++ke) {
        const int ex = seli[wv * 2 + ke];
        const float pw = selp[wv * 2 + ke];
        const float* A = Aup + (long long)ex * 2048;  // [64 o][32 i]
        const float* B = Bup + (long long)ex * 2048;  // [64 p][32 j]

        S3 x0 = split8(xA0, xA1);
        S3 x1 = split8(xB0, xB1);

        // ---- stage 1: W[i][p] = sum_j X[i][j] B[p][j]  (K=32, one MFMA-K) ----
        f4v wd[8];   // [mt 0..1][pt 0..3]
#pragma unroll
        for (int pt = 0; pt < 4; ++pt) {
            int base = (pt * 16 + m) * 32 + quad * 8;
            S3 bs = split8(*(const f4v*)(B + base), *(const f4v*)(B + base + 4));
            wd[0 * 4 + pt] = mfma6(x0, bs, zf);
            wd[1 * 4 + pt] = mfma6(x1, bs, zf);
        }
        // write (pw*W)^T fp32: lane holds W[i = mt*16+quad*4+r][p = pt*16+m]
        {
            const f4v pwv = {pw, pw, pw, pw};
#pragma unroll
            for (int mt = 0; mt < 2; ++mt)
#pragma unroll
                for (int pt = 0; pt < 4; ++pt) {
                    f4v w = wd[mt * 4 + pt] * pwv;
                    *(f4v*)&wtw[(pt * 16 + m) * 36 + mt * 16 + quad * 4] = w;
                }
        }

        // ---- stage 2: Y[o][p] += sum_i A[o][i] (pw*W)[i][p]  (K=32) ----
        // same-wave ds ordering guarantees write->read visibility (down_kernel
        // uses the identical pattern, verified).
#pragma unroll
        for (int pth = 0; pth < 2; ++pth) {
            int p0 = (pth * 2 + 0) * 16 + m;
            int p1 = (pth * 2 + 1) * 16 + m;
            S3 w0 = split8(*(const f4v*)&wtw[p0 * 36 + quad * 8],
                           *(const f4v*)&wtw[p0 * 36 + quad * 8 + 4]);
            S3 w1 = split8(*(const f4v*)&wtw[p1 * 36 + quad * 8],
                           *(const f4v*)&wtw[p1 * 36 + quad * 8 + 4]);
#pragma unroll
            for (int ot = 0; ot < 4; ++ot) {
                int abase = (ot * 16 + m) * 32 + quad * 8;
                S3 as = split8(*(const f4v*)(A + abase), *(const f4v*)(A + abase + 4));
                Y[ot * 4 + pth * 2 + 0] = mfma6(as, w0, Y[ot * 4 + pth * 2 + 0]);
                Y[ot * 4 + pth * 2 + 1] = mfma6(as, w1, Y[ot * 4 + pth * 2 + 1]);
            }
        }
    }

    // ---- epilogue: Y[o = ot*16+quad*4+r][p = pt*16+m] -> gelu -> h ----
    {
        float* hrow = h + tok * 4096;
#pragma unroll
        for (int ot = 0; ot < 4; ++ot)
#pragma unroll
            for (int r = 0; r < 4; ++r) {
                int o = ot * 16 + quad * 4 + r;
#pragma unroll
                for (int pt = 0; pt < 4; ++pt) {
                    int f = o * 64 + pt * 16 + m;
                    float v = Y[ot * 4 + pt][r] * sc_up;
                    float z = v + bias_up[f];
                    hrow[f] = 0.5f * z * (1.0f + erff(z * 0.70710678118654752f));
                }
            }
    }
}

// ---------------------------------------------------------------------------
// Kernel 2: down router + down experts (bf16 MFMA, per-wave)
// [VERBATIM R0 baseline — measured ~187.5 us]
// ---------------------------------------------------------------------------
__global__ __launch_bounds__(256, 2) void down_kernel(
    const float* __restrict__ h,        // [N][4096]
    const float* __restrict__ Wdn,      // [64][4096]
    const float* __restrict__ Adn,      // [64][32][64]
    const float* __restrict__ Bdn,      // [64][32][64]
    const float* __restrict__ scale_dn, // [1]
    const float* __restrict__ bias_dn,  // [1024]
    float* __restrict__ out)            // [N][1024]
{
    __shared__ __align__(16) float wcs[64 * 68];    // 17.4 KB
    __shared__ __align__(16) float hcs[16 * 68];    // 4.3 KB
    __shared__ __align__(16) float lp[4 * 16 * 64]; // 16.4 KB
    __shared__ __align__(16) float logits[TB2 * 64];
    __shared__ __align__(16) short wt[4][32 * 72];  // per-wave W^T bf16 [p][i]
    __shared__ int   seli[TB2 * 2];
    __shared__ float selp[TB2 * 2];

    const int tid = threadIdx.x;
    const long long tokbase = (long long)blockIdx.x * TB2;

    // ---- down router: 4 experts per thread, k-slice = one float4 ----
    const int e4 = tid & 15, jsl = tid >> 4; // jsl 0..15
    float r0[16], r1[16], r2[16], r3[16];
#pragma unroll
    for (int t = 0; t < 16; ++t) { r0[t] = 0.f; r1[t] = 0.f; r2[t] = 0.f; r3[t] = 0.f; }

    for (int kc = 0; kc < 4096; kc += 64) {
        __syncthreads();
#pragma unroll
        for (int r = 0; r < 4; ++r) {
            int row = (tid >> 4) + r * 16;
            int col = (tid & 15) * 4;
            *(float4*)&wcs[row * 68 + col] = ldg4(&Wdn[row * 4096 + kc + col]);
        }
        {
            int t = tid >> 4, c = (tid & 15) * 4;
            *(float4*)&hcs[t * 68 + c] = ldg4(&h[(tokbase + t) * 4096 + kc + c]);
        }
        __syncthreads();
        const int kk = jsl * 4;
        float4 w0 = *(float4*)&wcs[(e4)      * 68 + kk];
        float4 w1 = *(float4*)&wcs[(e4 + 16) * 68 + kk];
        float4 w2 = *(float4*)&wcs[(e4 + 32) * 68 + kk];
        float4 w3 = *(float4*)&wcs[(e4 + 48) * 68 + kk];
#pragma unroll
        for (int t = 0; t < 16; ++t) {
            float4 hv = *(float4*)&hcs[t * 68 + kk];
            r0[t] += w0.x * hv.x + w0.y * hv.y + w0.z * hv.z + w0.w * hv.w;
            r1[t] += w1.x * hv.x + w1.y * hv.y + w1.z * hv.z + w1.w * hv.w;
            r2[t] += w2.x * hv.x + w2.y * hv.y + w2.z * hv.z + w2.w * hv.w;
            r3[t] += w3.x * hv.x + w3.y * hv.y + w3.z * hv.z + w3.w * hv.w;
        }
    }
    // reduce over the wave's 4 k-slices (lanes xor 16, 32)
#pragma unroll
    for (int t = 0; t < 16; ++t) {
        r0[t] += __shfl_xor(r0[t], 16); r0[t] += __shfl_xor(r0[t], 32);
        r1[t] += __shfl_xor(r1[t], 16); r1[t] += __shfl_xor(r1[t], 32);
        r2[t] += __shfl_xor(r2[t], 16); r2[t] += __shfl_xor(r2[t], 32);
        r3[t] += __shfl_xor(r3[t], 16); r3[t] += __shfl_xor(r3[t], 32);
    }
    {
        const int wv = tid >> 6, g = (tid >> 4) & 3;
        float* dst = &lp[wv * 1024];
        if (g == 0) {
#pragma unroll
            for (int t = 0; t < 16; ++t) dst[t * 64 + e4] = r0[t];
        } else if (g == 1) {
#pragma unroll
            for (int t = 0; t < 16; ++t) dst[t * 64 + 16 + e4] = r1[t];
        } else if (g == 2) {
#pragma unroll
            for (int t = 0; t < 16; ++t) dst[t * 64 + 32 + e4] = r2[t];
        } else {
#pragma unroll
            for (int t = 0; t < 16; ++t) dst[t * 64 + 48 + e4] = r3[t];
        }
    }
    __syncthreads();
#pragma unroll
    for (int q = 0; q < 4; ++q) {
        int pair = tid + q * 256;
        logits[pair] = lp[0 * 1024 + pair] + lp[1 * 1024 + pair] +
                       lp[2 * 1024 + pair] + lp[3 * 1024 + pair];
    }
    __syncthreads();
    if (tid < TB2) {
        const float* lg = &logits[tid * 64];
        float v0 = -1e30f; int i0 = 0;
        for (int q = 0; q < 64; ++q) { float v = lg[q]; if (v > v0) { v0 = v; i0 = q; } }
        float v1 = -1e30f; int i1 = 0;
        for (int q = 0; q < 64; ++q) { if (q == i0) continue; float v = lg[q]; if (v > v1) { v1 = v; i1 = q; } }
        float r = expf(v1 - v0);
        float inv = 1.f / (1.f + r);
        seli[tid * 2] = i0; seli[tid * 2 + 1] = i1;
        selp[tid * 2] = inv; selp[tid * 2 + 1] = r * inv;
    }
    __syncthreads();

    // ---- down experts: per-wave MFMA, no barriers ----
    const float sc_dn = scale_dn[0];
    const int wv = tid >> 6;
    const int lane = tid & 63;
    const int m = lane & 15, quad = lane >> 4;
    short* wtw = &wt[wv][0]; // [32 p][72 i] bf16

    const f4v zf = {0.f, 0.f, 0.f, 0.f};

#pragma unroll 1
    for (int tt = 0; tt < 4; ++tt) {
        const int t = wv * 4 + tt;
        const long long tok = tokbase + t;
        const float* xrow = h + tok * 4096; // X[64 i][64 j], j contiguous

        s8v xf[8];
#pragma unroll
        for (int mt = 0; mt < 4; ++mt)
#pragma unroll
            for (int ks = 0; ks < 2; ++ks) {
                int base = (mt * 16 + m) * 64 + ks * 32 + quad * 8;
                xf[mt * 2 + ks] = pack8(ldg4(xrow + base), ldg4(xrow + base + 4));
            }

        f4v y00 = zf, y01 = zf, y10 = zf, y11 = zf;

        for (int ke = 0; ke < 2; ++ke) {
            const int ex = seli[t * 2 + ke];
            const float pw = selp[t * 2 + ke];
            const float* A = Adn + ex * 2048; // [32 o][64 i]
            const float* B = Bdn + ex * 2048; // [32 p][64 j]

            // ---- stage 1: W[i][p] = sum_j X[i][j] * B[p][j] ----
            f4v wd[8];
#pragma unroll
            for (int ks = 0; ks < 2; ++ks) {
                s8v bf0, bf1;
                {
                    int base = (0 * 16 + m) * 64 + ks * 32 + quad * 8;
                    bf0 = pack8(ldg4(B + base), ldg4(B + base + 4));
                    base = (1 * 16 + m) * 64 + ks * 32 + quad * 8;
                    bf1 = pack8(ldg4(B + base), ldg4(B + base + 4));
                }
#pragma unroll
                for (int mt = 0; mt < 4; ++mt) {
                    wd[mt * 2 + 0] = __builtin_amdgcn_mfma_f32_16x16x32_bf16(
                        xf[mt * 2 + ks], bf0, ks == 0 ? zf : wd[mt * 2 + 0], 0, 0, 0);
                    wd[mt * 2 + 1] = __builtin_amdgcn_mfma_f32_16x16x32_bf16(
                        xf[mt * 2 + ks], bf1, ks == 0 ? zf : wd[mt * 2 + 1], 0, 0, 0);
                }
            }
#pragma unroll
            for (int mt = 0; mt < 4; ++mt)
#pragma unroll
                for (int pt = 0; pt < 2; ++pt) {
                    f4v w = wd[mt * 2 + pt];
                    s4v s;
                    s[0] = f2b(w[0] * pw); s[1] = f2b(w[1] * pw);
                    s[2] = f2b(w[2] * pw); s[3] = f2b(w[3] * pw);
                    *(s4v*)&wtw[(pt * 16 + m) * 72 + mt * 16 + quad * 4] = s;
                }

            // ---- stage 2: Y[o][p] += sum_i A[o][i] * (pw*W)[i][p] ----
#pragma unroll
            for (int ks = 0; ks < 2; ++ks) {
                s8v wb0 = *(s8v*)&wtw[(0 * 16 + m) * 72 + ks * 32 + quad * 8];
                s8v wb1 = *(s8v*)&wtw[(1 * 16 + m) * 72 + ks * 32 + quad * 8];
                s8v af0, af1;
                {
                    int base = (0 * 16 + m) * 64 + ks * 32 + quad * 8;
                    af0 = pack8(ldg4(A + base), ldg4(A + base + 4));
                    base = (1 * 16 + m) * 64 + ks * 32 + quad * 8;
                    af1 = pack8(ldg4(A + base), ldg4(A + base + 4));
                }
                y00 = __builtin_amdgcn_mfma_f32_16x16x32_bf16(af0, wb0, y00, 0, 0, 0);
                y01 = __builtin_amdgcn_mfma_f32_16x16x32_bf16(af0, wb1, y01, 0, 0, 0);
                y10 = __builtin_amdgcn_mfma_f32_16x16x32_bf16(af1, wb0, y10, 0, 0, 0);
                y11 = __builtin_amdgcn_mfma_f32_16x16x32_bf16(af1, wb1, y11, 0, 0, 0);
            }
        }

        float* orow = out + tok * 1024;
#pragma unroll
        for (int r = 0; r < 4; ++r) {
            int o0 = quad * 4 + r;
            int f00 = o0 * 32 + m;
            orow[f00]            = y00[r] * sc_dn + bias_dn[f00];
            orow[f00 + 16]       = y01[r] * sc_dn + bias_dn[f00 + 16];
            int f10 = (o0 + 16) * 32 + m;
            orow[f10]            = y10[r] * sc_dn + bias_dn[f10];
            orow[f10 + 16]       = y11[r] * sc_dn + bias_dn[f10 + 16];
        }
    }
}

extern "C" void kernel_launch(void* const* d_in, const int* in_sizes, int n_in,
                              void* d_out, int out_size, void* d_ws, size_t ws_size,
                              hipStream_t stream) {
    const float* x   = (const float*)d_in[0];
    const float* Wup = (const float*)d_in[1];
    const float* Aup = (const float*)d_in[2];
    const float* Bup = (const float*)d_in[3];
    const float* scu = (const float*)d_in[4];
    const float* biu = (const float*)d_in[5];
    const float* Wdn = (const float*)d_in[6];
    const float* Adn = (const float*)d_in[7];
    const float* Bdn = (const float*)d_in[8];
    const float* scd = (const float*)d_in[9];
    const float* bid = (const float*)d_in[10];
    float* out = (float*)d_out;
    float* h   = (float*)d_ws;   // [N][4096] fp32 = 128 MB for N=8192

    const int N = in_sizes[0] / 1024;

    hipLaunchKernelGGL(up_kernel, dim3(N / TB1), dim3(256), 0, stream,
                       x, Wup, Aup, Bup, scu, biu, h);
    hipLaunchKernelGGL(down_kernel, dim3(N / TB2), dim3(256), 0, stream,
                       h, Wdn, Adn, Bdn, scd, bid, out);
}